// Round 8
// baseline (425.548 us; speedup 1.0000x reference)
//
#include <hip/hip_runtime.h>
#include <hip/hip_bf16.h>
#include <stdint.h>
#include <stddef.h>

typedef __hip_bfloat16 bf16_t;
typedef __attribute__((ext_vector_type(8))) short short8;
typedef __attribute__((ext_vector_type(4))) short short4v;
typedef __attribute__((ext_vector_type(4))) float floatx4;

#define EMBED 1024
#define NHEAD 16
#define HDIM  64
#define BATCH 2
#define SEQ   2048
#define MTOT  (BATCH*SEQ)
#define NEG_INF (-1e30f)
#define QSCALE 0.1803368801111244f   // 0.125 * log2(e): S emerges in exp2 domain

#define MFMA16(a,b,c) __builtin_amdgcn_mfma_f32_16x16x32_bf16(a,b,c,0,0,0)

static __device__ __forceinline__ short bf16_bits(float x) {
    return __builtin_bit_cast(short, __float2bfloat16(x));
}

// async global->LDS, 16B per lane; lds ptr must be wave-uniform (HW: base + lane*16)
static __device__ __forceinline__ void async_ld16(const bf16_t* g, short* l) {
    __builtin_amdgcn_global_load_lds(
        (const __attribute__((address_space(1))) void*)g,
        (__attribute__((address_space(3))) void*)l,
        16, 0, 0);
}

static __device__ __forceinline__ void store_out(float* p, float v)  { *p = v; }
static __device__ __forceinline__ void store_out(bf16_t* p, float v) { *p = __float2bfloat16(v); }

// fp32 -> bf16 (RTNE) for q,k,v (4M each) and Wq,Wk,Wv,Wo (1M each). grid.y selects tensor.
__global__ __launch_bounds__(256)
void cvt_all(const float* __restrict__ q, const float* __restrict__ k, const float* __restrict__ v,
             const float* __restrict__ wq, const float* __restrict__ wk,
             const float* __restrict__ wv, const float* __restrict__ wo,
             bf16_t* __restrict__ Qx, bf16_t* __restrict__ Kx, bf16_t* __restrict__ Vx,
             bf16_t* __restrict__ Wqb, bf16_t* __restrict__ Wkb,
             bf16_t* __restrict__ Wvb, bf16_t* __restrict__ Wob)
{
    const float* s; bf16_t* d; int n;
    switch (blockIdx.y) {
        case 0:  s = q;  d = Qx;  n = MTOT * EMBED;  break;
        case 1:  s = k;  d = Kx;  n = MTOT * EMBED;  break;
        case 2:  s = v;  d = Vx;  n = MTOT * EMBED;  break;
        case 3:  s = wq; d = Wqb; n = EMBED * EMBED; break;
        case 4:  s = wk; d = Wkb; n = EMBED * EMBED; break;
        case 5:  s = wv; d = Wvb; n = EMBED * EMBED; break;
        default: s = wo; d = Wob; n = EMBED * EMBED; break;
    }
    const int i4 = (int)blockIdx.x * 256 + (int)threadIdx.x;   // float4 index
    if (i4 * 4 < n) {
        const float4 f = ((const float4*)s)[i4];
        short4v o;
        o[0] = bf16_bits(f.x); o[1] = bf16_bits(f.y);
        o[2] = bf16_bits(f.z); o[3] = bf16_bits(f.w);
        ((short4v*)d)[i4] = o;
    }
}

// C[M,N] = A[M,K] @ W[N,K]^T + bias, bf16 in, fp32 accumulate, output scaled by oscale.
// M=4096, N=K=1024 fixed. 128x128 tile, BK=32, 256 thr (4 waves 2x2). m97 structure.
// VT=true: write output transposed per-batch as Ct[b*1024 + n][s].
template <typename OutT, bool VT>
static __device__ __forceinline__ void gemm_tile_128(
    const bf16_t* __restrict__ A, const bf16_t* __restrict__ W,
    const float* __restrict__ bias, OutT* __restrict__ C, float oscale)
{
    const int N = 1024, K = 1024;
    __shared__ alignas(16) short As[128*32];
    __shared__ alignas(16) short Bs[128*32];

    const int tid  = threadIdx.x;
    const int wave = tid >> 6;
    const int lane = tid & 63;
    const int nbn = N >> 7;                 // 8
    const int bm = (int)blockIdx.x / nbn;
    const int bn = (int)blockIdx.x % nbn;
    const int m0 = bm << 7, n0 = bn << 7;

    const int wm = ((wave >> 1) & 1) << 6;  // 0 / 64
    const int wn = (wave & 1) << 6;

    floatx4 acc[4][4] = {};

    const int srow = (wave << 5) + (lane >> 2);   // staging row within tile
    const int scol = (lane & 3) << 3;             // element col: 0,8,16,24
    const bf16_t* gA = A + (size_t)(m0 + srow) * K + scol;
    const bf16_t* gB = W + (size_t)(n0 + srow) * K + scol;
    short* lA0 = &As[(wave << 10)];
    short* lA1 = &As[(wave << 10) + 512];
    short* lB0 = &Bs[(wave << 10)];
    short* lB1 = &Bs[(wave << 10) + 512];

    const int fr = lane & 15;
    const int fk = (lane >> 4) << 3;

    for (int k0 = 0; k0 < K; k0 += 32) {
        __syncthreads();
        async_ld16(gA,                  lA0);
        async_ld16(gA + (size_t)16 * K, lA1);
        async_ld16(gB,                  lB0);
        async_ld16(gB + (size_t)16 * K, lB1);
        gA += 32; gB += 32;
        __syncthreads();                      // drains vmcnt before barrier (m97-verified)

        short8 af[4], bfr[4];
        #pragma unroll
        for (int i = 0; i < 4; ++i)
            af[i] = *(const short8*)&As[(wm + (i << 4) + fr) * 32 + fk];
        #pragma unroll
        for (int j = 0; j < 4; ++j)
            bfr[j] = *(const short8*)&Bs[(wn + (j << 4) + fr) * 32 + fk];
        #pragma unroll
        for (int i = 0; i < 4; ++i)
            #pragma unroll
            for (int j = 0; j < 4; ++j)
                acc[i][j] = MFMA16(af[i], bfr[j], acc[i][j]);
    }

    // epilogue: C/D layout col=lane&15, row=quad*4+r
    const int q4 = (lane >> 4) << 2;
    #pragma unroll
    for (int j = 0; j < 4; ++j) {
        const int n = n0 + wn + (j << 4) + fr;
        const float bv = bias[n];
        #pragma unroll
        for (int i = 0; i < 4; ++i) {
            const int mb = m0 + wm + (i << 4) + q4;
            if (VT) {
                const int bb = mb >> 11, ss = mb & 2047;
                short4v pk;
                #pragma unroll
                for (int r = 0; r < 4; ++r)
                    pk[r] = bf16_bits((acc[i][j][r] + bv) * oscale);
                *(short4v*)((bf16_t*)C + ((size_t)(bb * 1024 + n) << 11) + ss) = pk;
            } else {
                #pragma unroll
                for (int r = 0; r < 4; ++r)
                    store_out(&C[(size_t)(mb + r) * N + n], (acc[i][j][r] + bv) * oscale);
            }
        }
    }
}

// 64x128 tile variant (M-tile 64): doubles block count for the N=1024 out-proj so
// 2 blocks/CU co-reside and hide each other's barrier drains. 4 waves as 2x2 of 32x64.
template <typename OutT>
static __device__ __forceinline__ void gemm_tile_64(
    const bf16_t* __restrict__ A, const bf16_t* __restrict__ W,
    const float* __restrict__ bias, OutT* __restrict__ C, float oscale)
{
    const int N = 1024, K = 1024;
    __shared__ alignas(16) short As[64*32];
    __shared__ alignas(16) short Bs[128*32];

    const int tid  = threadIdx.x;
    const int wave = tid >> 6;
    const int lane = tid & 63;
    const int bm = (int)blockIdx.x >> 3;
    const int bn = (int)blockIdx.x & 7;
    const int m0 = bm << 6, n0 = bn << 7;

    const int wm = ((wave >> 1) & 1) << 5;  // 0 / 32
    const int wn = (wave & 1) << 6;         // 0 / 64

    floatx4 acc[2][4] = {};

    const int srowA = (wave << 4) + (lane >> 2);  // 16 rows/wave
    const int srowB = (wave << 5) + (lane >> 2);  // 32 rows/wave
    const int scol  = (lane & 3) << 3;
    const bf16_t* gA = A + (size_t)(m0 + srowA) * K + scol;
    const bf16_t* gB = W + (size_t)(n0 + srowB) * K + scol;
    short* lA  = &As[(wave << 9)];
    short* lB0 = &Bs[(wave << 10)];
    short* lB1 = &Bs[(wave << 10) + 512];

    const int fr = lane & 15;
    const int fk = (lane >> 4) << 3;

    for (int k0 = 0; k0 < K; k0 += 32) {
        __syncthreads();
        async_ld16(gA,                  lA);
        async_ld16(gB,                  lB0);
        async_ld16(gB + (size_t)16 * K, lB1);
        gA += 32; gB += 32;
        __syncthreads();

        short8 af[2], bfr[4];
        #pragma unroll
        for (int i = 0; i < 2; ++i)
            af[i] = *(const short8*)&As[(wm + (i << 4) + fr) * 32 + fk];
        #pragma unroll
        for (int j = 0; j < 4; ++j)
            bfr[j] = *(const short8*)&Bs[(wn + (j << 4) + fr) * 32 + fk];
        #pragma unroll
        for (int i = 0; i < 2; ++i)
            #pragma unroll
            for (int j = 0; j < 4; ++j)
                acc[i][j] = MFMA16(af[i], bfr[j], acc[i][j]);
    }

    const int q4 = (lane >> 4) << 2;
    #pragma unroll
    for (int j = 0; j < 4; ++j) {
        const int n = n0 + wn + (j << 4) + fr;
        const float bv = bias[n];
        #pragma unroll
        for (int i = 0; i < 2; ++i) {
            const int mb = m0 + wm + (i << 4) + q4;
            #pragma unroll
            for (int r = 0; r < 4; ++r)
                store_out(&C[(size_t)(mb + r) * N + n], (acc[i][j][r] + bv) * oscale);
        }
    }
}

__global__ __launch_bounds__(256)
void qkv_proj(const bf16_t* __restrict__ xq, const bf16_t* __restrict__ xk,
              const bf16_t* __restrict__ xv,
              const bf16_t* __restrict__ Wq, const bf16_t* __restrict__ Wk,
              const bf16_t* __restrict__ Wv,
              const float* __restrict__ bq, const float* __restrict__ bk,
              const float* __restrict__ bv,
              bf16_t* __restrict__ Qp, bf16_t* __restrict__ Kp, bf16_t* __restrict__ Vtp)
{
    if (blockIdx.z == 0)      gemm_tile_128<bf16_t, false>(xq, Wq, bq, Qp, QSCALE);  // Q pre-scaled
    else if (blockIdx.z == 1) gemm_tile_128<bf16_t, false>(xk, Wk, bk, Kp, 1.0f);
    else                      gemm_tile_128<bf16_t, true >(xv, Wv, bv, Vtp, 1.0f);
}

__global__ __launch_bounds__(256)
void out_proj(const bf16_t* __restrict__ AO, const bf16_t* __restrict__ Wo,
              const float* __restrict__ bo, float* __restrict__ out)
{
    gemm_tile_64<float>(AO, Wo, bo, out, 1.0f);
}

// Flash attention, causal. S^T (D = K·Q^T) and O^T (D = V^T·P^T): one q-row per lane
// (q = lane&15); m is lane-scalar; l via all-ones-A MFMA into o5. P round-trips through
// wave-local LDS [16 q][stride 40] (conflict-free both ways). No barriers.
// LINE SHARING (R8): the 4 waves of a block take CONSECUTIVE q-tiles {4g..4g+3} and
// sweep the SAME kv chunk sequence in convoy — K/V cachelines are shared 4-ways via
// L1/miss-merge (R7 showed per-CU line-request throughput is the limiter: time was
// invariant to occupancy and HBM traffic while all pipes idled). Waves early-exit
// past their own diagonal (~2% extra masked work, block-max trip count).
// K is PREFETCHED one chunk ahead in registers (hides L2 latency inside the chain);
// V loads sit at chunk-top, covered by QK+softmax.
// Heavy-first order: gg=0 -> g=31. XCD pinning: idx ≡ bh (mod 8).
__global__ __launch_bounds__(256, 4)
void attn_causal(const bf16_t* __restrict__ Qp, const bf16_t* __restrict__ Kp,
                 const bf16_t* __restrict__ Vt, bf16_t* __restrict__ AO)
{
    __shared__ alignas(16) short Pbuf[4][16 * 40];   // per-wave P staging, 1280 B

    const int tid  = threadIdx.x;
    const int wave = tid >> 6;
    const int lane = tid & 63;
    const int idx = (int)blockIdx.x;
    const int bh  = (idx & 7) | ((idx >> 8) << 3);   // xcd-pinned head index 0..31
    const int gg  = (idx >> 3) & 31;
    const int g   = 31 - gg;                         // heavy blocks dispatch first
    const int b   = bh >> 4, h = bh & 15;
    const int t   = (g << 2) + wave;                 // this wave's q-tile 0..127
    const int q0  = t << 4;

    const int fr   = lane & 15;
    const int quad = lane >> 4;
    const int fk   = quad << 3;

    // Q B-frags (B[k=d][n=q]): lane holds Q[q0+fr][fk+j] (+32)
    const bf16_t* Qrow = Qp + (size_t)(b * SEQ + q0 + fr) * EMBED + h * HDIM;
    const short8 aq0 = *(const short8*)(Qrow + fk);
    const short8 aq1 = *(const short8*)(Qrow + 32 + fk);

    const bf16_t* Kbase = Kp + (size_t)(b * SEQ) * EMBED + h * HDIM;
    const bf16_t* Vbase = Vt + ((size_t)(b * 1024 + h * HDIM) << 11);

    short8 ones;                  // all-ones A-frag for the l-row MFMA
    #pragma unroll
    for (int j = 0; j < 8; ++j) ones[j] = (short)0x3F80;   // bf16 1.0

    floatx4 o[4] = {};            // O^T[d=t*16+quad*4+r][q=fr]
    floatx4 o5 = {};              // l accumulator: every row = l(q=fr)
    float m = NEG_INF;

    short* Pw = &Pbuf[wave][0];
    const int nch = (t >> 1) + 1;        // chunks incl. the masked diagonal one

    // preload K chunk 0
    const bf16_t* Kr0 = Kbase + (size_t)fr * EMBED;
    const bf16_t* Kr1 = Kr0 + (size_t)16 * EMBED;
    short8 kc0 = *(const short8*)(Kr0 + fk);
    short8 kc1 = *(const short8*)(Kr0 + 32 + fk);
    short8 kc2 = *(const short8*)(Kr1 + fk);
    short8 kc3 = *(const short8*)(Kr1 + 32 + fk);

    for (int c = 0; c < nch; ++c) {
        const int kv0 = c << 5;
        const bool masked = (c == nch - 1);

        // prefetch next chunk's K (clamped on last iter: re-reads same lines, L1 hit)
        const int kvn = masked ? kv0 : (kv0 + 32);
        const bf16_t* Kn0 = Kbase + (size_t)(kvn + fr) * EMBED;
        const bf16_t* Kn1 = Kn0 + (size_t)16 * EMBED;
        const short8 kn0 = *(const short8*)(Kn0 + fk);
        const short8 kn1 = *(const short8*)(Kn0 + 32 + fk);
        const short8 kn2 = *(const short8*)(Kn1 + fk);
        const short8 kn3 = *(const short8*)(Kn1 + 32 + fk);

        // V A-frags for current chunk: independent of QK/softmax -> latency covered
        short8 vf[4];
        #pragma unroll
        for (int tt = 0; tt < 4; ++tt)
            vf[tt] = *(const short8*)(Vbase + (((size_t)((tt << 4) + fr)) << 11) + kv0 + fk);

        floatx4 s0 = {}, s1 = {};
        s0 = MFMA16(kc0, aq0, s0);
        s0 = MFMA16(kc1, aq1, s0);
        s1 = MFMA16(kc2, aq0, s1);
        s1 = MFMA16(kc3, aq1, s1);

        // S^T layout: lane holds S[kv0 + quad*4+r (+16)][q0+fr], exp2-domain
        float v0[4], v1[4], mx = NEG_INF;
        #pragma unroll
        for (int r = 0; r < 4; ++r) {
            float a = s0[r], bb = s1[r];
            if (masked) {
                const int q = q0 + fr, kva = kv0 + (quad << 2) + r;
                if (kva > q)      a  = NEG_INF;
                if (kva + 16 > q) bb = NEG_INF;
            }
            v0[r] = a; v1[r] = bb;
            mx = fmaxf(mx, fmaxf(a, bb));
        }
        mx = fmaxf(mx, __shfl_xor(mx, 16, 64));
        mx = fmaxf(mx, __shfl_xor(mx, 32, 64));

        const float mnew = fmaxf(m, mx);
        const float al = __builtin_amdgcn_exp2f(m - mnew);
        m = mnew;
        #pragma unroll
        for (int r = 0; r < 4; ++r) {
            v0[r] = __builtin_amdgcn_exp2f(v0[r] - mnew);
            v1[r] = __builtin_amdgcn_exp2f(v1[r] - mnew);
        }
        #pragma unroll
        for (int tt = 0; tt < 4; ++tt)
            #pragma unroll
            for (int r = 0; r < 4; ++r)
                o[tt][r] *= al;              // al is lane-scalar (per q=fr)
        #pragma unroll
        for (int r = 0; r < 4; ++r)
            o5[r] *= al;

        // P staged as [q][kv] stride 40: write = S^T C-layout, read = B-frag (B[k=kv][n=q])
        short4v w0, w1;
        #pragma unroll
        for (int r = 0; r < 4; ++r) { w0[r] = bf16_bits(v0[r]); w1[r] = bf16_bits(v1[r]); }
        *(short4v*)&Pw[fr * 40 + (quad << 2)]      = w0;
        *(short4v*)&Pw[fr * 40 + 16 + (quad << 2)] = w1;
        const short8 pb = *(const short8*)&Pw[fr * 40 + fk];

        o5 = MFMA16(ones, pb, o5);           // l += column-sums of P^T
        #pragma unroll
        for (int tt = 0; tt < 4; ++tt)
            o[tt] = MFMA16(vf[tt], pb, o[tt]);

        kc0 = kn0; kc1 = kn1; kc2 = kn2; kc3 = kn3;
    }

    const float linv = 1.0f / o5[0];         // all rows of o5 equal l(q=fr)

    // store O^T: lane owns row q=q0+fr, d = tt*16+quad*4+r -> 4x 8B stores
    bf16_t* Arow = AO + (size_t)(b * SEQ + q0 + fr) * EMBED + h * HDIM;
    #pragma unroll
    for (int tt = 0; tt < 4; ++tt) {
        short4v pk;
        #pragma unroll
        for (int r = 0; r < 4; ++r)
            pk[r] = bf16_bits(o[tt][r] * linv);
        *(short4v*)(Arow + (tt << 4) + (quad << 2)) = pk;
    }
}

extern "C" void kernel_launch(void* const* d_in, const int* in_sizes, int n_in,
                              void* d_out, int out_size, void* d_ws, size_t ws_size,
                              hipStream_t stream)
{
    (void)in_sizes; (void)n_in; (void)out_size; (void)ws_size;
    const float* q  = (const float*)d_in[0];
    const float* k  = (const float*)d_in[1];
    const float* v  = (const float*)d_in[2];
    const float* Wq = (const float*)d_in[3];
    const float* bq = (const float*)d_in[4];
    const float* Wk = (const float*)d_in[5];
    const float* bk = (const float*)d_in[6];
    const float* Wv = (const float*)d_in[7];
    const float* bv = (const float*)d_in[8];
    const float* Wo = (const float*)d_in[9];
    const float* bo = (const float*)d_in[10];
    // d_in[11] = attn_mask: fixed causal tril, handled analytically.

    const size_t NX = (size_t)MTOT * EMBED;   // 4M
    const size_t NW = (size_t)EMBED * EMBED;  // 1M
    bf16_t* Qx  = (bf16_t*)d_ws;
    bf16_t* Kx  = Qx  + NX;
    bf16_t* Vx  = Kx  + NX;
    bf16_t* Wqb = Vx  + NX;
    bf16_t* Wkb = Wqb + NW;
    bf16_t* Wvb = Wkb + NW;
    bf16_t* Wob = Wvb + NW;
    bf16_t* Qp  = Wob + NW;
    bf16_t* Kp  = Qp  + NX;
    bf16_t* Vtp = Kp  + NX;   // transposed: [b*1024 + d_global][s]
    bf16_t* AO  = Vtp + NX;   // total 32M bf16 = 64 MB

    dim3 blk(256);
    cvt_all<<<dim3(4096, 7), blk, 0, stream>>>(q, k, v, Wq, Wk, Wv, Wo,
                                               Qx, Kx, Vx, Wqb, Wkb, Wvb, Wob);
    qkv_proj<<<dim3(256, 1, 3), blk, 0, stream>>>(Qx, Kx, Vx, Wqb, Wkb, Wvb,
                                                  bq, bk, bv, Qp, Kp, Vtp);
    attn_causal<<<dim3(1024), blk, 0, stream>>>(Qp, Kp, Vtp, AO);
    out_proj<<<dim3(512), blk, 0, stream>>>(AO, Wob, bo, (float*)d_out);
}

// Round 9
// 338.316 us; speedup vs baseline: 1.2578x; 1.2578x over previous
//
#include <hip/hip_runtime.h>
#include <hip/hip_bf16.h>
#include <stdint.h>
#include <stddef.h>

typedef __hip_bfloat16 bf16_t;
typedef __attribute__((ext_vector_type(8))) short short8;
typedef __attribute__((ext_vector_type(4))) short short4v;
typedef __attribute__((ext_vector_type(4))) float floatx4;

#define EMBED 1024
#define NHEAD 16
#define HDIM  64
#define BATCH 2
#define SEQ   2048
#define MTOT  (BATCH*SEQ)
#define NEG_INF (-1e30f)
#define QSCALE 0.1803368801111244f   // 0.125 * log2(e): S emerges in exp2 domain

#define MFMA16(a,b,c) __builtin_amdgcn_mfma_f32_16x16x32_bf16(a,b,c,0,0,0)

static __device__ __forceinline__ short bf16_bits(float x) {
    return __builtin_bit_cast(short, __float2bfloat16(x));
}

// async global->LDS, 16B per lane; lds ptr must be wave-uniform (HW: base + lane*16)
static __device__ __forceinline__ void async_ld16(const bf16_t* g, short* l) {
    __builtin_amdgcn_global_load_lds(
        (const __attribute__((address_space(1))) void*)g,
        (__attribute__((address_space(3))) void*)l,
        16, 0, 0);
}

static __device__ __forceinline__ void store_out(float* p, float v)  { *p = v; }
static __device__ __forceinline__ void store_out(bf16_t* p, float v) { *p = __float2bfloat16(v); }

// fp32 -> bf16 (RTNE) for q,k,v (4M each) and Wq,Wk,Wv,Wo (1M each). grid.y selects tensor.
__global__ __launch_bounds__(256)
void cvt_all(const float* __restrict__ q, const float* __restrict__ k, const float* __restrict__ v,
             const float* __restrict__ wq, const float* __restrict__ wk,
             const float* __restrict__ wv, const float* __restrict__ wo,
             bf16_t* __restrict__ Qx, bf16_t* __restrict__ Kx, bf16_t* __restrict__ Vx,
             bf16_t* __restrict__ Wqb, bf16_t* __restrict__ Wkb,
             bf16_t* __restrict__ Wvb, bf16_t* __restrict__ Wob)
{
    const float* s; bf16_t* d; int n;
    switch (blockIdx.y) {
        case 0:  s = q;  d = Qx;  n = MTOT * EMBED;  break;
        case 1:  s = k;  d = Kx;  n = MTOT * EMBED;  break;
        case 2:  s = v;  d = Vx;  n = MTOT * EMBED;  break;
        case 3:  s = wq; d = Wqb; n = EMBED * EMBED; break;
        case 4:  s = wk; d = Wkb; n = EMBED * EMBED; break;
        case 5:  s = wv; d = Wvb; n = EMBED * EMBED; break;
        default: s = wo; d = Wob; n = EMBED * EMBED; break;
    }
    const int i4 = (int)blockIdx.x * 256 + (int)threadIdx.x;   // float4 index
    if (i4 * 4 < n) {
        const float4 f = ((const float4*)s)[i4];
        short4v o;
        o[0] = bf16_bits(f.x); o[1] = bf16_bits(f.y);
        o[2] = bf16_bits(f.z); o[3] = bf16_bits(f.w);
        ((short4v*)d)[i4] = o;
    }
}

// C[M,N] = A[M,K] @ W[N,K]^T + bias, bf16 in, fp32 accumulate, output scaled by oscale.
// M=4096, N=K=1024 fixed. 128x128 tile, BK=32, 256 thr (4 waves 2x2). m97 structure.
// VT=true: write output transposed per-batch as Ct[b*1024 + n][s].
template <typename OutT, bool VT>
static __device__ __forceinline__ void gemm_tile_128(
    const bf16_t* __restrict__ A, const bf16_t* __restrict__ W,
    const float* __restrict__ bias, OutT* __restrict__ C, float oscale)
{
    const int N = 1024, K = 1024;
    __shared__ alignas(16) short As[128*32];
    __shared__ alignas(16) short Bs[128*32];

    const int tid  = threadIdx.x;
    const int wave = tid >> 6;
    const int lane = tid & 63;
    const int nbn = N >> 7;                 // 8
    const int bm = (int)blockIdx.x / nbn;
    const int bn = (int)blockIdx.x % nbn;
    const int m0 = bm << 7, n0 = bn << 7;

    const int wm = ((wave >> 1) & 1) << 6;  // 0 / 64
    const int wn = (wave & 1) << 6;

    floatx4 acc[4][4] = {};

    const int srow = (wave << 5) + (lane >> 2);   // staging row within tile
    const int scol = (lane & 3) << 3;             // element col: 0,8,16,24
    const bf16_t* gA = A + (size_t)(m0 + srow) * K + scol;
    const bf16_t* gB = W + (size_t)(n0 + srow) * K + scol;
    short* lA0 = &As[(wave << 10)];
    short* lA1 = &As[(wave << 10) + 512];
    short* lB0 = &Bs[(wave << 10)];
    short* lB1 = &Bs[(wave << 10) + 512];

    const int fr = lane & 15;
    const int fk = (lane >> 4) << 3;

    for (int k0 = 0; k0 < K; k0 += 32) {
        __syncthreads();
        async_ld16(gA,                  lA0);
        async_ld16(gA + (size_t)16 * K, lA1);
        async_ld16(gB,                  lB0);
        async_ld16(gB + (size_t)16 * K, lB1);
        gA += 32; gB += 32;
        __syncthreads();                      // drains vmcnt before barrier (m97-verified)

        short8 af[4], bfr[4];
        #pragma unroll
        for (int i = 0; i < 4; ++i)
            af[i] = *(const short8*)&As[(wm + (i << 4) + fr) * 32 + fk];
        #pragma unroll
        for (int j = 0; j < 4; ++j)
            bfr[j] = *(const short8*)&Bs[(wn + (j << 4) + fr) * 32 + fk];
        #pragma unroll
        for (int i = 0; i < 4; ++i)
            #pragma unroll
            for (int j = 0; j < 4; ++j)
                acc[i][j] = MFMA16(af[i], bfr[j], acc[i][j]);
    }

    // epilogue: C/D layout col=lane&15, row=quad*4+r
    const int q4 = (lane >> 4) << 2;
    #pragma unroll
    for (int j = 0; j < 4; ++j) {
        const int n = n0 + wn + (j << 4) + fr;
        const float bv = bias[n];
        #pragma unroll
        for (int i = 0; i < 4; ++i) {
            const int mb = m0 + wm + (i << 4) + q4;
            if (VT) {
                const int bb = mb >> 11, ss = mb & 2047;
                short4v pk;
                #pragma unroll
                for (int r = 0; r < 4; ++r)
                    pk[r] = bf16_bits((acc[i][j][r] + bv) * oscale);
                *(short4v*)((bf16_t*)C + ((size_t)(bb * 1024 + n) << 11) + ss) = pk;
            } else {
                #pragma unroll
                for (int r = 0; r < 4; ++r)
                    store_out(&C[(size_t)(mb + r) * N + n], (acc[i][j][r] + bv) * oscale);
            }
        }
    }
}

// 64x128 tile variant: 512 blocks for the N=1024 out-proj, 2 blocks/CU.
template <typename OutT>
static __device__ __forceinline__ void gemm_tile_64(
    const bf16_t* __restrict__ A, const bf16_t* __restrict__ W,
    const float* __restrict__ bias, OutT* __restrict__ C, float oscale)
{
    const int N = 1024, K = 1024;
    __shared__ alignas(16) short As[64*32];
    __shared__ alignas(16) short Bs[128*32];

    const int tid  = threadIdx.x;
    const int wave = tid >> 6;
    const int lane = tid & 63;
    const int bm = (int)blockIdx.x >> 3;
    const int bn = (int)blockIdx.x & 7;
    const int m0 = bm << 6, n0 = bn << 7;

    const int wm = ((wave >> 1) & 1) << 5;  // 0 / 32
    const int wn = (wave & 1) << 6;         // 0 / 64

    floatx4 acc[2][4] = {};

    const int srowA = (wave << 4) + (lane >> 2);  // 16 rows/wave
    const int srowB = (wave << 5) + (lane >> 2);  // 32 rows/wave
    const int scol  = (lane & 3) << 3;
    const bf16_t* gA = A + (size_t)(m0 + srowA) * K + scol;
    const bf16_t* gB = W + (size_t)(n0 + srowB) * K + scol;
    short* lA  = &As[(wave << 9)];
    short* lB0 = &Bs[(wave << 10)];
    short* lB1 = &Bs[(wave << 10) + 512];

    const int fr = lane & 15;
    const int fk = (lane >> 4) << 3;

    for (int k0 = 0; k0 < K; k0 += 32) {
        __syncthreads();
        async_ld16(gA,                  lA);
        async_ld16(gB,                  lB0);
        async_ld16(gB + (size_t)16 * K, lB1);
        gA += 32; gB += 32;
        __syncthreads();

        short8 af[2], bfr[4];
        #pragma unroll
        for (int i = 0; i < 2; ++i)
            af[i] = *(const short8*)&As[(wm + (i << 4) + fr) * 32 + fk];
        #pragma unroll
        for (int j = 0; j < 4; ++j)
            bfr[j] = *(const short8*)&Bs[(wn + (j << 4) + fr) * 32 + fk];
        #pragma unroll
        for (int i = 0; i < 2; ++i)
            #pragma unroll
            for (int j = 0; j < 4; ++j)
                acc[i][j] = MFMA16(af[i], bfr[j], acc[i][j]);
    }

    const int q4 = (lane >> 4) << 2;
    #pragma unroll
    for (int j = 0; j < 4; ++j) {
        const int n = n0 + wn + (j << 4) + fr;
        const float bv = bias[n];
        #pragma unroll
        for (int i = 0; i < 2; ++i) {
            const int mb = m0 + wm + (i << 4) + q4;
            #pragma unroll
            for (int r = 0; r < 4; ++r)
                store_out(&C[(size_t)(mb + r) * N + n], (acc[i][j][r] + bv) * oscale);
        }
    }
}

__global__ __launch_bounds__(256)
void qkv_proj(const bf16_t* __restrict__ xq, const bf16_t* __restrict__ xk,
              const bf16_t* __restrict__ xv,
              const bf16_t* __restrict__ Wq, const bf16_t* __restrict__ Wk,
              const bf16_t* __restrict__ Wv,
              const float* __restrict__ bq, const float* __restrict__ bk,
              const float* __restrict__ bv,
              bf16_t* __restrict__ Qp, bf16_t* __restrict__ Kp, bf16_t* __restrict__ Vtp)
{
    if (blockIdx.z == 0)      gemm_tile_128<bf16_t, false>(xq, Wq, bq, Qp, QSCALE);  // Q pre-scaled
    else if (blockIdx.z == 1) gemm_tile_128<bf16_t, false>(xk, Wk, bk, Kp, 1.0f);
    else                      gemm_tile_128<bf16_t, true >(xv, Wv, bv, Vtp, 1.0f);
}

__global__ __launch_bounds__(256)
void out_proj(const bf16_t* __restrict__ AO, const bf16_t* __restrict__ Wo,
              const float* __restrict__ bo, float* __restrict__ out)
{
    gemm_tile_64<float>(AO, Wo, bo, out, 1.0f);
}

// Flash attention, causal. S^T (K·Q^T) + O^T (V^T·P^T): one q-row per lane (q=lane&15);
// m lane-scalar; l via all-ones-A MFMA (o5). P round-trips wave-local LDS [16][40].
// R9: block = 4 waves on ONE 16-row q-tile, KV split 4 ways (wave w: chunks c≡w mod 4).
// All 4 waves sweep the SAME K/V lines within a ~1-chunk window -> ~4x fewer per-CU
// line requests (the R7/R8-identified limiter) while keeping high wave count.
// Merge: 4-way online-softmax combine via LDS (union'd with P-buf) + 2 uniform barriers.
// Grid 4096 (128 tiles x 32 bh) = 16 queued/CU, 6 resident (bounds 256,6) -> backfill
// fixes causal imbalance; heavy-first (t = 127 - ...); XCD pinning: idx ≡ bh (mod 8).
__global__ __launch_bounds__(256, 6)
void attn_causal(const bf16_t* __restrict__ Qp, const bf16_t* __restrict__ Kp,
                 const bf16_t* __restrict__ Vt, bf16_t* __restrict__ AO)
{
    __shared__ union {
        short P[4][16 * 40];       // per-wave P staging (loop phase)
        float O[4][16][64];        // per-wave O^T dump (merge phase), 16 KB
    } U;
    __shared__ float Mb[4][16], Lb[4][16];

    const int tid  = threadIdx.x;
    const int wave = tid >> 6;
    const int lane = tid & 63;
    const int idx = (int)blockIdx.x;
    const int bh  = (idx & 7) | (((idx >> 10) & 3) << 3);   // xcd-pinned head 0..31
    const int t   = 127 - ((idx >> 3) & 127);               // heavy tiles dispatch first
    const int b   = bh >> 4, h = bh & 15;
    const int q0  = t << 4;

    const int fr   = lane & 15;
    const int quad = lane >> 4;
    const int fk   = quad << 3;

    // Q B-frags (B[k=d][n=q]): lane holds Q[q0+fr][fk+j] (+32)
    const bf16_t* Qrow = Qp + (size_t)(b * SEQ + q0 + fr) * EMBED + h * HDIM;
    const short8 aq0 = *(const short8*)(Qrow + fk);
    const short8 aq1 = *(const short8*)(Qrow + 32 + fk);

    const bf16_t* Kbase = Kp + (size_t)(b * SEQ) * EMBED + h * HDIM;
    const bf16_t* Vbase = Vt + ((size_t)(b * 1024 + h * HDIM) << 11);

    short8 ones;                  // all-ones A-frag for the l-row MFMA
    #pragma unroll
    for (int j = 0; j < 8; ++j) ones[j] = (short)0x3F80;   // bf16 1.0

    floatx4 o[4] = {};            // O^T[d=tt*16+quad*4+r][q=fr]
    floatx4 o5 = {};              // l accumulator: every component = l(q=fr)
    float m = NEG_INF;

    short* Pw = &U.P[wave][0];
    const int cd = t >> 1;        // diagonal (masked) chunk index

    for (int c = wave; c <= cd; c += 4) {
        const int kv0 = c << 5;
        const bool masked = (c == cd);

        // V A-frags first: independent of QK/softmax -> latency covered
        short8 vf[4];
        #pragma unroll
        for (int tt = 0; tt < 4; ++tt)
            vf[tt] = *(const short8*)(Vbase + (((size_t)((tt << 4) + fr)) << 11) + kv0 + fk);

        // K A-frags (A[m=kv][k=d]): lane holds K[kv0+(sub*16)+fr][fk+j]
        const bf16_t* Kr0 = Kbase + (size_t)(kv0 + fr) * EMBED;
        const bf16_t* Kr1 = Kr0 + (size_t)16 * EMBED;
        const short8 k00 = *(const short8*)(Kr0 + fk);
        const short8 k01 = *(const short8*)(Kr0 + 32 + fk);
        const short8 k10 = *(const short8*)(Kr1 + fk);
        const short8 k11 = *(const short8*)(Kr1 + 32 + fk);

        floatx4 s0 = {}, s1 = {};
        s0 = MFMA16(k00, aq0, s0);
        s0 = MFMA16(k01, aq1, s0);
        s1 = MFMA16(k10, aq0, s1);
        s1 = MFMA16(k11, aq1, s1);

        // S^T layout: lane holds S[kv0 + quad*4+r (+16)][q0+fr], exp2-domain
        float v0[4], v1[4], mx = NEG_INF;
        #pragma unroll
        for (int r = 0; r < 4; ++r) {
            float a = s0[r], bb = s1[r];
            if (masked) {
                const int qq = q0 + fr, kva = kv0 + (quad << 2) + r;
                if (kva > qq)      a  = NEG_INF;
                if (kva + 16 > qq) bb = NEG_INF;
            }
            v0[r] = a; v1[r] = bb;
            mx = fmaxf(mx, fmaxf(a, bb));
        }
        mx = fmaxf(mx, __shfl_xor(mx, 16, 64));
        mx = fmaxf(mx, __shfl_xor(mx, 32, 64));

        const float mnew = fmaxf(m, mx);
        const float al = __builtin_amdgcn_exp2f(m - mnew);
        m = mnew;
        #pragma unroll
        for (int r = 0; r < 4; ++r) {
            v0[r] = __builtin_amdgcn_exp2f(v0[r] - mnew);
            v1[r] = __builtin_amdgcn_exp2f(v1[r] - mnew);
        }
        #pragma unroll
        for (int tt = 0; tt < 4; ++tt)
            #pragma unroll
            for (int r = 0; r < 4; ++r)
                o[tt][r] *= al;              // al is lane-scalar (per q=fr)
        #pragma unroll
        for (int r = 0; r < 4; ++r)
            o5[r] *= al;

        // P staged as [q][kv] stride 40: write = S^T C-layout, read = B-frag (B[k=kv][n=q])
        short4v w0, w1;
        #pragma unroll
        for (int r = 0; r < 4; ++r) { w0[r] = bf16_bits(v0[r]); w1[r] = bf16_bits(v1[r]); }
        *(short4v*)&Pw[fr * 40 + (quad << 2)]      = w0;
        *(short4v*)&Pw[fr * 40 + 16 + (quad << 2)] = w1;
        const short8 pb = *(const short8*)&Pw[fr * 40 + fk];

        o5 = MFMA16(ones, pb, o5);           // l += column-sums of P^T
        #pragma unroll
        for (int tt = 0; tt < 4; ++tt)
            o[tt] = MFMA16(vf[tt], pb, o[tt]);
    }

    __syncthreads();   // all P-buf (union) uses complete before O dump
    #pragma unroll
    for (int tt = 0; tt < 4; ++tt)
        *(floatx4*)&U.O[wave][fr][(tt << 4) + (quad << 2)] = o[tt];
    if (quad == 0) { Mb[wave][fr] = m; Lb[wave][fr] = o5[0]; }
    __syncthreads();

    // 4-way online-softmax merge, all 256 threads: thread -> (q = tid>>4, 4 d's)
    const int q  = tid >> 4;
    const int ds = (tid & 15) << 2;
    float mw0 = Mb[0][q], mw1 = Mb[1][q], mw2 = Mb[2][q], mw3 = Mb[3][q];
    const float mm = fmaxf(fmaxf(mw0, mw1), fmaxf(mw2, mw3));
    float acc0 = 0.f, acc1 = 0.f, acc2 = 0.f, acc3 = 0.f, ltot = 0.f;
    #pragma unroll
    for (int w = 0; w < 4; ++w) {
        const float mwv = (w == 0) ? mw0 : (w == 1) ? mw1 : (w == 2) ? mw2 : mw3;
        const float wt = __builtin_amdgcn_exp2f(mwv - mm);
        ltot += Lb[w][q] * wt;
        const floatx4 ov = *(const floatx4*)&U.O[w][q][ds];
        acc0 += ov[0] * wt; acc1 += ov[1] * wt;
        acc2 += ov[2] * wt; acc3 += ov[3] * wt;
    }
    const float inv = 1.0f / ltot;
    short4v pk;
    pk[0] = bf16_bits(acc0 * inv); pk[1] = bf16_bits(acc1 * inv);
    pk[2] = bf16_bits(acc2 * inv); pk[3] = bf16_bits(acc3 * inv);
    *(short4v*)(AO + (size_t)(b * SEQ + q0 + q) * EMBED + h * HDIM + ds) = pk;
}

extern "C" void kernel_launch(void* const* d_in, const int* in_sizes, int n_in,
                              void* d_out, int out_size, void* d_ws, size_t ws_size,
                              hipStream_t stream)
{
    (void)in_sizes; (void)n_in; (void)out_size; (void)ws_size;
    const float* q  = (const float*)d_in[0];
    const float* k  = (const float*)d_in[1];
    const float* v  = (const float*)d_in[2];
    const float* Wq = (const float*)d_in[3];
    const float* bq = (const float*)d_in[4];
    const float* Wk = (const float*)d_in[5];
    const float* bk = (const float*)d_in[6];
    const float* Wv = (const float*)d_in[7];
    const float* bv = (const float*)d_in[8];
    const float* Wo = (const float*)d_in[9];
    const float* bo = (const float*)d_in[10];
    // d_in[11] = attn_mask: fixed causal tril, handled analytically.

    const size_t NX = (size_t)MTOT * EMBED;   // 4M
    const size_t NW = (size_t)EMBED * EMBED;  // 1M
    bf16_t* Qx  = (bf16_t*)d_ws;
    bf16_t* Kx  = Qx  + NX;
    bf16_t* Vx  = Kx  + NX;
    bf16_t* Wqb = Vx  + NX;
    bf16_t* Wkb = Wqb + NW;
    bf16_t* Wvb = Wkb + NW;
    bf16_t* Wob = Wvb + NW;
    bf16_t* Qp  = Wob + NW;
    bf16_t* Kp  = Qp  + NX;
    bf16_t* Vtp = Kp  + NX;   // transposed: [b*1024 + d_global][s]
    bf16_t* AO  = Vtp + NX;   // total 32M bf16 = 64 MB

    dim3 blk(256);
    cvt_all<<<dim3(4096, 7), blk, 0, stream>>>(q, k, v, Wq, Wk, Wv, Wo,
                                               Qx, Kx, Vx, Wqb, Wkb, Wvb, Wob);
    qkv_proj<<<dim3(256, 1, 3), blk, 0, stream>>>(Qx, Kx, Vx, Wqb, Wkb, Wvb,
                                                  bq, bk, bv, Qp, Kp, Vtp);
    attn_causal<<<dim3(4096), blk, 0, stream>>>(Qp, Kp, Vtp, AO);
    out_proj<<<dim3(512), blk, 0, stream>>>(AO, Wob, bo, (float*)d_out);
}